// Round 15
// baseline (68.745 us; speedup 1.0000x reference)
//
#include <hip/hip_runtime.h>
#include <hip/hip_bf16.h>
#include <math.h>

#define BB 16
#define CC 128
#define NN 2048
#define CQ 32   // C/4

typedef __attribute__((ext_vector_type(8))) short bf16x8;
typedef __attribute__((ext_vector_type(4))) float f32x4;
typedef __attribute__((ext_vector_type(16))) float f32x16;

__device__ __forceinline__ ushort f2b(float f) {
    __hip_bfloat16 h = __float2bfloat16(f);
    return *reinterpret_cast<ushort*>(&h);
}
__device__ __forceinline__ float b2f(ushort u) {
    union { unsigned u; float f; } v; v.u = ((unsigned)u) << 16;
    return v.f;
}
__device__ __forceinline__ bf16x8 as_b8(uint4 u) {
    union { uint4 u; bf16x8 b; } v; v.u = u; return v.b;
}
__device__ __forceinline__ bf16x8 as_b8_2(uint2 a, uint2 b) {
    return as_b8(make_uint4(a.x, a.y, b.x, b.y));
}
__device__ __forceinline__ float fexp2(float x) {
    return __builtin_amdgcn_exp2f(x);   // v_exp_f32: 2^x
}

// ---------------- workspace layout (float granularity offsets) ----------------
// Qt  : bf16 [B][N][32]   off 0          (wq pre-scaled by sqrt(log2 e))
// Vb  : bf16 [B][128][N]  off 524,288
// RSI : f32  [B][N]       off 4,718,592
#define OFF_VB  524288
#define OFF_RSI 4718592

#define QSCALE 1.2011224087864498f   // sqrt(log2(e)); E comes out scaled by log2(e)

// K1: MFMA projection. Qt[b,n,d] (d<32, scaled), Vb[b,d,n] = wv.x + bv.
__global__ __launch_bounds__(256) void k_proj(const float* __restrict__ x,
        const float* __restrict__ wq, const float* __restrict__ wv,
        const float* __restrict__ bv, ushort* __restrict__ Qt, ushort* __restrict__ Vb) {
    __shared__ ushort Wl[160][136];
    __shared__ ushort Xs[64][136];   // [n][c] bf16
    int bid = (blockIdx.x & 7) * 64 + (blockIdx.x >> 3);   // XCD-chunked swizzle
    int b  = bid >> 5;
    int n0 = (bid & 31) << 6;
    int tid = threadIdx.x;
    #pragma unroll
    for (int k = 0; k < 20; ++k) {
        int idx = k * 256 + tid;
        int r = idx >> 5, c4 = (idx & 31) << 2;
        const float* srcw = (r < 32) ? (wq + r * 128 + c4) : (wv + (r - 32) * 128 + c4);
        float4 w4 = *(const float4*)srcw;
        float s = (r < 32) ? QSCALE : 1.0f;
        *(ushort4*)&Wl[r][c4] = make_ushort4(f2b(w4.x * s), f2b(w4.y * s),
                                             f2b(w4.z * s), f2b(w4.w * s));
    }
    const float* xb = x + (size_t)b * CC * NN;
    for (int idx = tid; idx < 2048; idx += 256) {
        int c = idx >> 4, n4 = (idx & 15) << 2;
        float4 xv = *(const float4*)&xb[c * NN + n0 + n4];
        Xs[n4][c]     = f2b(xv.x);
        Xs[n4 + 1][c] = f2b(xv.y);
        Xs[n4 + 2][c] = f2b(xv.z);
        Xs[n4 + 3][c] = f2b(xv.w);
    }
    __syncthreads();
    int w = tid >> 6, l = tid & 63, lr = l & 15, lg = l >> 4;
    f32x4 zero = {0.f, 0.f, 0.f, 0.f};
    int nn = n0 + w * 16 + lr;
    for (int dt = 0; dt < 10; ++dt) {
        f32x4 acc = zero;
        #pragma unroll
        for (int k = 0; k < 4; ++k) {
            bf16x8 a  = *(const bf16x8*)&Wl[dt * 16 + lr][k * 32 + lg * 8];
            bf16x8 bx = *(const bf16x8*)&Xs[w * 16 + lr][k * 32 + lg * 8];
            acc = __builtin_amdgcn_mfma_f32_16x16x32_bf16(a, bx, acc, 0, 0, 0);
        }
        if (dt < 2) {
            ushort4 p = make_ushort4(f2b(acc[0]), f2b(acc[1]), f2b(acc[2]), f2b(acc[3]));
            *(ushort4*)&Qt[(size_t)(b * NN + nn) * CQ + dt * 16 + lg * 4] = p;
        } else {
            #pragma unroll
            for (int i = 0; i < 4; ++i) {
                int vd = (dt - 2) * 16 + lg * 4 + i;
                Vb[(size_t)(b * CC + vd) * NN + nn] = f2b(acc[i] + bv[vd]);
            }
        }
    }
}

// K2: row softmax denominators. E pre-scaled by log2e -> exp2. RSI = 1/rowsum.
__global__ __launch_bounds__(512) void k_rowstats(const ushort* __restrict__ Qt,
        float* __restrict__ RSI) {
    __shared__ ushort Qm[128][36];
    __shared__ float Sred[2][64];
    int bid = (blockIdx.x & 7) * 64 + (blockIdx.x >> 3);
    int b  = bid >> 5;
    int n0 = (bid & 31) << 6;
    int tid = threadIdx.x;
    int w = tid >> 6, l = tid & 63, lr = l & 15, lg = l >> 4;
    int wn = w & 3, wm = w >> 2;
    const ushort* Qtb = Qt + (size_t)b * NN * CQ;
    bf16x8 aq = *(const bf16x8*)&Qtb[(size_t)(n0 + wn * 16 + lr) * CQ + lg * 8];
    int sr = tid >> 2, sc = (tid & 3) * 8;
    uint4 q0 = *(const uint4*)&Qtb[(size_t)sr * CQ + sc];
    float S[4] = {0.f, 0.f, 0.f, 0.f};
    f32x4 zero = {0.f, 0.f, 0.f, 0.f};
    for (int t = 0; t < 16; ++t) {
        __syncthreads();
        *(uint4*)&Qm[sr][sc] = q0;
        __syncthreads();
        if (t < 15)
            q0 = *(const uint4*)&Qtb[(size_t)((t + 1) * 128 + sr) * CQ + sc];
        #pragma unroll
        for (int mi = 0; mi < 4; ++mi) {
            bf16x8 bq = *(const bf16x8*)&Qm[(wm * 4 + mi) * 16 + lr][lg * 8];
            f32x4 e = __builtin_amdgcn_mfma_f32_16x16x32_bf16(aq, bq, zero, 0, 0, 0);
            S[0] += fexp2(e[0]); S[1] += fexp2(e[1]);
            S[2] += fexp2(e[2]); S[3] += fexp2(e[3]);
        }
    }
    #pragma unroll
    for (int d = 1; d < 16; d <<= 1) {
        #pragma unroll
        for (int i = 0; i < 4; ++i) S[i] += __shfl_xor(S[i], d);
    }
    if (lr == 0) {
        #pragma unroll
        for (int i = 0; i < 4; ++i) Sred[wm][wn * 16 + lg * 4 + i] = S[i];
    }
    __syncthreads();
    if (tid < 64)
        RSI[b * NN + n0 + tid] = 1.f / (Sred[0][tid] + Sred[1][tid]);
}

// K3: attn + PV + fused final. m-tile 128, 768 thr, grid 256.
// QUAD-buffered Vs/Ws, ONE barrier per 2 tiles (17 barriers total).
// Producers (w 0-7): E + softmax + Ws write + V staging for tiles 2p+2, 2p+3.
// Consumers (w 8-11): PV 32x32x16 on tiles 2p, 2p+1.
// Epilogue: Us = bf16(x - XR) in LDS (alias Vs); wt GEMM (A from global f32).
__global__ __launch_bounds__(768, 3) void k_attn_pv(const ushort* __restrict__ Qt,
        const ushort* __restrict__ Vb, const float* __restrict__ RSI,
        const float* __restrict__ x, const float* __restrict__ wt,
        const float* __restrict__ bt, const float* __restrict__ gamma,
        const float* __restrict__ beta, const float* __restrict__ bn_mean,
        const float* __restrict__ bn_var, float* __restrict__ out) {
    __shared__ ushort Vs[4][128][68];   // [buf][d][n]; epilogue: Us[m][c] stride 132
    __shared__ ushort Ws[4][128][68];   // [buf][m][n]
    __shared__ float csred[4][128];
    __shared__ float csum[128];
    __shared__ float fAl[128], fBl[128];
    int bid = (blockIdx.x & 7) * 32 + (blockIdx.x >> 3);   // XCD-chunked swizzle
    int b  = bid >> 4;
    int m0 = (bid & 15) << 7;
    int tid = threadIdx.x;
    int w = tid >> 6, l = tid & 63, lr = l & 15, lg = l >> 4;
    const ushort* Qtb = Qt + (size_t)b * NN * CQ;
    const ushort* Vbb = Vb + (size_t)b * CC * NN;
    const float*  RSb = RSI + (size_t)b * NN;
    const float*  xb  = x   + (size_t)b * CC * NN;
    float*        outb = out + (size_t)b * CC * NN;
    f32x4 zero = {0.f, 0.f, 0.f, 0.f};
    bool producer = (w < 8);

    if (tid < 128) {
        float A = gamma[tid] * rsqrtf(bn_var[tid] + 1e-5f);
        fAl[tid] = A;
        fBl[tid] = (bt[tid] - bn_mean[tid]) * A + beta[tid];
    }

    // ---------------- producer state ----------------
    int wn = w & 3, mh = w >> 2;            // n-strip, m-half
    bf16x8 bm[4];
    float cs[4] = {0.f, 0.f, 0.f, 0.f};
    int sv = 0, shv = 0;
    const ushort* vsrc = nullptr;
    // ---------------- consumer state ----------------
    int cw = w - 8;
    int dh = cw >> 1, mh2 = cw & 1;         // d-half, m-half
    int ar = l & 31, kh = l >> 5;
    f32x16 pacc00, pacc01, pacc10, pacc11;

    if (producer) {
        #pragma unroll
        for (int mi = 0; mi < 4; ++mi)
            bm[mi] = *(const bf16x8*)&Qtb[(size_t)(m0 + (mh * 4 + mi) * 16 + lr) * CQ + lg * 8];
        sv = tid >> 2; shv = (tid & 3) * 16;   // V row, 16-col chunk
        vsrc = Vbb + (size_t)sv * NN + shv;
    } else {
        #pragma unroll
        for (int r = 0; r < 16; ++r) {
            pacc00[r] = 0.f; pacc01[r] = 0.f; pacc10[r] = 0.f; pacc11[r] = 0.f;
        }
    }

    // producer phase body: build tiles tA and tA+1 (V + E + Ws)
    auto produce2 = [&](int tA) {
        int tB = tA + 1;
        int bqA = tA & 3, bqB = tB & 3;
        int ntA = tA * 64, ntB = tB * 64;
        // issue ALL global loads first (latency spans the phase)
        uint4 va0 = *(const uint4*)(vsrc + ntA);
        uint4 va1 = *(const uint4*)(vsrc + ntA + 8);
        uint4 vb0 = *(const uint4*)(vsrc + ntB);
        uint4 vb1 = *(const uint4*)(vsrc + ntB + 8);
        bf16x8 aqA = *(const bf16x8*)&Qtb[(size_t)(ntA + wn * 16 + lr) * CQ + lg * 8];
        bf16x8 aqB = *(const bf16x8*)&Qtb[(size_t)(ntB + wn * 16 + lr) * CQ + lg * 8];
        float4 r4A = *(const float4*)&RSb[ntA + wn * 16 + lg * 4];
        float4 r4B = *(const float4*)&RSb[ntB + wn * 16 + lg * 4];
        int nb = wn * 16 + lg * 4;
        #pragma unroll
        for (int mi = 0; mi < 4; ++mi) {
            f32x4 e = __builtin_amdgcn_mfma_f32_16x16x32_bf16(aqA, bm[mi], zero, 0, 0, 0);
            float w0 = fexp2(e[0]) * r4A.x;
            float w1 = fexp2(e[1]) * r4A.y;
            float w2 = fexp2(e[2]) * r4A.z;
            float w3 = fexp2(e[3]) * r4A.w;
            cs[mi] += w0 + w1 + w2 + w3;
            *(ushort4*)&Ws[bqA][(mh * 4 + mi) * 16 + lr][nb] =
                make_ushort4(f2b(w0), f2b(w1), f2b(w2), f2b(w3));
        }
        {
            ushort* dst = &Vs[bqA][sv][shv];
            *(uint2*)(dst)      = make_uint2(va0.x, va0.y);
            *(uint2*)(dst + 4)  = make_uint2(va0.z, va0.w);
            *(uint2*)(dst + 8)  = make_uint2(va1.x, va1.y);
            *(uint2*)(dst + 12) = make_uint2(va1.z, va1.w);
        }
        #pragma unroll
        for (int mi = 0; mi < 4; ++mi) {
            f32x4 e = __builtin_amdgcn_mfma_f32_16x16x32_bf16(aqB, bm[mi], zero, 0, 0, 0);
            float w0 = fexp2(e[0]) * r4B.x;
            float w1 = fexp2(e[1]) * r4B.y;
            float w2 = fexp2(e[2]) * r4B.z;
            float w3 = fexp2(e[3]) * r4B.w;
            cs[mi] += w0 + w1 + w2 + w3;
            *(ushort4*)&Ws[bqB][(mh * 4 + mi) * 16 + lr][nb] =
                make_ushort4(f2b(w0), f2b(w1), f2b(w2), f2b(w3));
        }
        {
            ushort* dst = &Vs[bqB][sv][shv];
            *(uint2*)(dst)      = make_uint2(vb0.x, vb0.y);
            *(uint2*)(dst + 4)  = make_uint2(vb0.z, vb0.w);
            *(uint2*)(dst + 8)  = make_uint2(vb1.x, vb1.y);
            *(uint2*)(dst + 12) = make_uint2(vb1.z, vb1.w);
        }
    };
    // consumer body: PV on tile u
    auto consume = [&](int u) {
        int bq = u & 3;
        #pragma unroll
        for (int kk = 0; kk < 4; ++kk) {
            const ushort* vp0 = &Vs[bq][dh * 64 + ar][kk * 16 + kh * 8];
            const ushort* vp1 = &Vs[bq][dh * 64 + 32 + ar][kk * 16 + kh * 8];
            uint2 a0 = *(const uint2*)vp0; uint2 a1 = *(const uint2*)(vp0 + 4);
            uint2 a2 = *(const uint2*)vp1; uint2 a3 = *(const uint2*)(vp1 + 4);
            bf16x8 va0 = as_b8_2(a0, a1);
            bf16x8 va1 = as_b8_2(a2, a3);
            const ushort* wp0 = &Ws[bq][mh2 * 64 + ar][kk * 16 + kh * 8];
            const ushort* wp1 = &Ws[bq][mh2 * 64 + 32 + ar][kk * 16 + kh * 8];
            uint2 b0 = *(const uint2*)wp0; uint2 b1 = *(const uint2*)(wp0 + 4);
            uint2 c0 = *(const uint2*)wp1; uint2 c1 = *(const uint2*)(wp1 + 4);
            bf16x8 wb0 = as_b8_2(b0, b1);
            bf16x8 wb1 = as_b8_2(c0, c1);
            pacc00 = __builtin_amdgcn_mfma_f32_32x32x16_bf16(va0, wb0, pacc00, 0, 0, 0);
            pacc01 = __builtin_amdgcn_mfma_f32_32x32x16_bf16(va0, wb1, pacc01, 0, 0, 0);
            pacc10 = __builtin_amdgcn_mfma_f32_32x32x16_bf16(va1, wb0, pacc10, 0, 0, 0);
            pacc11 = __builtin_amdgcn_mfma_f32_32x32x16_bf16(va1, wb1, pacc11, 0, 0, 0);
        }
    };

    // prologue: tiles 0,1 -> bufs 0,1
    if (producer) produce2(0);
    __syncthreads();
    // 16 phases: consumers on {2p,2p+1}, producers on {2p+2,2p+3}
    for (int p = 0; p < 16; ++p) {
        if (producer) {
            if (p < 15) produce2(2 * p + 2);
        } else {
            __builtin_amdgcn_s_setprio(1);
            consume(2 * p);
            consume(2 * p + 1);
            __builtin_amdgcn_s_setprio(0);
        }
        __syncthreads();
    }
    // ---- colsum reduce ----
    if (producer) {
        #pragma unroll
        for (int mi = 0; mi < 4; ++mi) {
            cs[mi] += __shfl_xor(cs[mi], 16);
            cs[mi] += __shfl_xor(cs[mi], 32);
        }
        if (lg == 0) {
            #pragma unroll
            for (int mi = 0; mi < 4; ++mi)
                csred[wn][(mh * 4 + mi) * 16 + lr] = cs[mi];
        }
    }
    __syncthreads();
    if (tid < 128) {
        float tot = csred[0][tid] + csred[1][tid] + csred[2][tid] + csred[3][tid];
        csum[tid] = 1.f / (1e-9f + tot);
    }
    __syncthreads();
    // ---- consumers: Us[m][c] = bf16(x - XR), aliased on Vs, stride 132 ----
    ushort* UsP = &Vs[0][0][0];
    if (!producer) {
        float inv0 = csum[mh2 * 64 + ar];
        float inv1 = csum[mh2 * 64 + 32 + ar];
        int mA = m0 + mh2 * 64 + ar;          // global m
        int mL = mh2 * 64 + ar;               // local m
        #pragma unroll
        for (int g = 0; g < 4; ++g) {
            int db = dh * 64 + 8 * g + 4 * kh;   // 4 consecutive d at db..db+3
            ushort4 u00, u01, u10, u11;
            #pragma unroll
            for (int j = 0; j < 4; ++j) {
                int r = 4 * g + j;
                float x00 = xb[(size_t)(db + j) * NN + mA];
                float x01 = xb[(size_t)(db + j) * NN + mA + 32];
                float x10 = xb[(size_t)(db + 32 + j) * NN + mA];
                float x11 = xb[(size_t)(db + 32 + j) * NN + mA + 32];
                ((ushort*)&u00)[j] = f2b(x00 - pacc00[r] * inv0);
                ((ushort*)&u01)[j] = f2b(x01 - pacc01[r] * inv1);
                ((ushort*)&u10)[j] = f2b(x10 - pacc10[r] * inv0);
                ((ushort*)&u11)[j] = f2b(x11 - pacc11[r] * inv1);
            }
            *(ushort4*)&UsP[mL * 132 + db]             = u00;
            *(ushort4*)&UsP[(mL + 32) * 132 + db]      = u01;
            *(ushort4*)&UsP[mL * 132 + db + 32]        = u10;
            *(ushort4*)&UsP[(mL + 32) * 132 + db + 32] = u11;
        }
    }
    __syncthreads();
    // ---- all waves: t = wt @ Us^T; out = x + relu(t*fA + fB) ----
    // A fragments built from global f32 wt (L2-hot), B from Us in LDS.
    for (int tile = w; tile < 16; tile += 12) {
        int rt = tile >> 2, mt = tile & 3;
        f32x16 acc;
        #pragma unroll
        for (int r = 0; r < 16; ++r) acc[r] = 0.f;
        #pragma unroll
        for (int kk = 0; kk < 8; ++kk) {
            const float* ap = &wt[(rt * 32 + ar) * 128 + kk * 16 + kh * 8];
            float4 wa = *(const float4*)ap;
            float4 wb4 = *(const float4*)(ap + 4);
            union { ushort u[8]; bf16x8 v; } af;
            af.u[0] = f2b(wa.x);  af.u[1] = f2b(wa.y);
            af.u[2] = f2b(wa.z);  af.u[3] = f2b(wa.w);
            af.u[4] = f2b(wb4.x); af.u[5] = f2b(wb4.y);
            af.u[6] = f2b(wb4.z); af.u[7] = f2b(wb4.w);
            const ushort* bp = &UsP[(mt * 32 + ar) * 132 + kk * 16 + kh * 8];
            uint2 b0 = *(const uint2*)bp; uint2 b1 = *(const uint2*)(bp + 4);
            acc = __builtin_amdgcn_mfma_f32_32x32x16_bf16(
                af.v, as_b8_2(b0, b1), acc, 0, 0, 0);
        }
        int m = m0 + mt * 32 + ar;
        #pragma unroll
        for (int g = 0; g < 4; ++g) {
            #pragma unroll
            for (int j = 0; j < 4; ++j) {
                int r = rt * 32 + j + 8 * g + 4 * kh;
                float t = acc[4 * g + j] * fAl[r] + fBl[r];
                t = fmaxf(t, 0.f);
                outb[(size_t)r * NN + m] = xb[(size_t)r * NN + m] + t;
            }
        }
    }
}

extern "C" void kernel_launch(void* const* d_in, const int* in_sizes, int n_in,
                              void* d_out, int out_size, void* d_ws, size_t ws_size,
                              hipStream_t stream) {
    const float* x       = (const float*)d_in[0];
    const float* wq      = (const float*)d_in[1];
    const float* wv      = (const float*)d_in[2];
    const float* bv      = (const float*)d_in[3];
    const float* wt      = (const float*)d_in[4];
    const float* bt      = (const float*)d_in[5];
    const float* gamma   = (const float*)d_in[6];
    const float* beta    = (const float*)d_in[7];
    const float* bn_mean = (const float*)d_in[8];
    const float* bn_var  = (const float*)d_in[9];
    float* out = (float*)d_out;
    float* ws  = (float*)d_ws;

    ushort* Qt   = (ushort*)ws;
    ushort* Vbp  = (ushort*)(ws + OFF_VB);
    float*  RSI  = ws + OFF_RSI;

    k_proj<<<BB * 32, 256, 0, stream>>>(x, wq, wv, bv, Qt, Vbp);
    k_rowstats<<<BB * 32, 512, 0, stream>>>(Qt, RSI);
    k_attn_pv<<<BB * 16, 768, 0, stream>>>(Qt, Vbp, RSI, x, wt, bt, gamma, beta,
                                           bn_mean, bn_var, out);
}

// Round 16
// 66.992 us; speedup vs baseline: 1.0262x; 1.0262x over previous
//
#include <hip/hip_runtime.h>
#include <hip/hip_bf16.h>
#include <hip/hip_fp8.h>
#include <math.h>

#define BB 16
#define CC 128
#define NN 2048
#define CQ 32   // C/4

typedef __attribute__((ext_vector_type(8))) short bf16x8;
typedef __attribute__((ext_vector_type(4))) float f32x4;
typedef __attribute__((ext_vector_type(16))) float f32x16;
typedef unsigned char uchar;

__device__ __forceinline__ ushort f2b(float f) {
    __hip_bfloat16 h = __float2bfloat16(f);
    return *reinterpret_cast<ushort*>(&h);
}
__device__ __forceinline__ float b2f(ushort u) {
    union { unsigned u; float f; } v; v.u = ((unsigned)u) << 16;
    return v.f;
}
__device__ __forceinline__ uchar f2q(float f) {
    __hip_fp8_e4m3 q(f);
    return *reinterpret_cast<uchar*>(&q);
}
__device__ __forceinline__ bf16x8 as_b8(uint4 u) {
    union { uint4 u; bf16x8 b; } v; v.u = u; return v.b;
}
__device__ __forceinline__ bf16x8 as_b8_2(uint2 a, uint2 b) {
    return as_b8(make_uint4(a.x, a.y, b.x, b.y));
}
__device__ __forceinline__ float fexp2(float x) {
    return __builtin_amdgcn_exp2f(x);   // v_exp_f32: 2^x
}
union U2L { uint2 u; long l; };

// ---------------- workspace layout (float granularity offsets) ----------------
// Qt  : bf16 [B][N][32]   off 0          (wq pre-scaled by sqrt(log2 e))
// Vb  : fp8  [B][128][N]  off 524,288    (e4m3)
// RSI : f32  [B][N]       off 4,718,592  (stores 256/rowsum)
#define OFF_VB  524288
#define OFF_RSI 4718592

#define QSCALE 1.2011224087864498f   // sqrt(log2(e)); E comes out scaled by log2(e)

// K1: MFMA projection. Qt[b,n,d] (d<32, scaled), Vb[b,d,n] = fp8(wv.x + bv).
__global__ __launch_bounds__(256) void k_proj(const float* __restrict__ x,
        const float* __restrict__ wq, const float* __restrict__ wv,
        const float* __restrict__ bv, ushort* __restrict__ Qt, uchar* __restrict__ Vb) {
    __shared__ ushort Wl[160][136];
    __shared__ ushort Xs[64][136];   // [n][c] bf16
    int bid = (blockIdx.x & 7) * 64 + (blockIdx.x >> 3);   // XCD-chunked swizzle
    int b  = bid >> 5;
    int n0 = (bid & 31) << 6;
    int tid = threadIdx.x;
    #pragma unroll
    for (int k = 0; k < 20; ++k) {
        int idx = k * 256 + tid;
        int r = idx >> 5, c4 = (idx & 31) << 2;
        const float* srcw = (r < 32) ? (wq + r * 128 + c4) : (wv + (r - 32) * 128 + c4);
        float4 w4 = *(const float4*)srcw;
        float s = (r < 32) ? QSCALE : 1.0f;
        *(ushort4*)&Wl[r][c4] = make_ushort4(f2b(w4.x * s), f2b(w4.y * s),
                                             f2b(w4.z * s), f2b(w4.w * s));
    }
    const float* xb = x + (size_t)b * CC * NN;
    for (int idx = tid; idx < 2048; idx += 256) {
        int c = idx >> 4, n4 = (idx & 15) << 2;
        float4 xv = *(const float4*)&xb[c * NN + n0 + n4];
        Xs[n4][c]     = f2b(xv.x);
        Xs[n4 + 1][c] = f2b(xv.y);
        Xs[n4 + 2][c] = f2b(xv.z);
        Xs[n4 + 3][c] = f2b(xv.w);
    }
    __syncthreads();
    int w = tid >> 6, l = tid & 63, lr = l & 15, lg = l >> 4;
    f32x4 zero = {0.f, 0.f, 0.f, 0.f};
    int nn = n0 + w * 16 + lr;
    for (int dt = 0; dt < 10; ++dt) {
        f32x4 acc = zero;
        #pragma unroll
        for (int k = 0; k < 4; ++k) {
            bf16x8 a  = *(const bf16x8*)&Wl[dt * 16 + lr][k * 32 + lg * 8];
            bf16x8 bx = *(const bf16x8*)&Xs[w * 16 + lr][k * 32 + lg * 8];
            acc = __builtin_amdgcn_mfma_f32_16x16x32_bf16(a, bx, acc, 0, 0, 0);
        }
        if (dt < 2) {
            ushort4 p = make_ushort4(f2b(acc[0]), f2b(acc[1]), f2b(acc[2]), f2b(acc[3]));
            *(ushort4*)&Qt[(size_t)(b * NN + nn) * CQ + dt * 16 + lg * 4] = p;
        } else {
            #pragma unroll
            for (int i = 0; i < 4; ++i) {
                int vd = (dt - 2) * 16 + lg * 4 + i;
                Vb[(size_t)(b * CC + vd) * NN + nn] = f2q(acc[i] + bv[vd]);
            }
        }
    }
}

// K2: row softmax denominators. RSI = 256/rowsum (fp8-W scaling folded in).
__global__ __launch_bounds__(512) void k_rowstats(const ushort* __restrict__ Qt,
        float* __restrict__ RSI) {
    __shared__ ushort Qm[128][36];
    __shared__ float Sred[2][64];
    int bid = (blockIdx.x & 7) * 64 + (blockIdx.x >> 3);
    int b  = bid >> 5;
    int n0 = (bid & 31) << 6;
    int tid = threadIdx.x;
    int w = tid >> 6, l = tid & 63, lr = l & 15, lg = l >> 4;
    int wn = w & 3, wm = w >> 2;
    const ushort* Qtb = Qt + (size_t)b * NN * CQ;
    bf16x8 aq = *(const bf16x8*)&Qtb[(size_t)(n0 + wn * 16 + lr) * CQ + lg * 8];
    int sr = tid >> 2, sc = (tid & 3) * 8;
    uint4 q0 = *(const uint4*)&Qtb[(size_t)sr * CQ + sc];
    float S[4] = {0.f, 0.f, 0.f, 0.f};
    f32x4 zero = {0.f, 0.f, 0.f, 0.f};
    for (int t = 0; t < 16; ++t) {
        __syncthreads();
        *(uint4*)&Qm[sr][sc] = q0;
        __syncthreads();
        if (t < 15)
            q0 = *(const uint4*)&Qtb[(size_t)((t + 1) * 128 + sr) * CQ + sc];
        #pragma unroll
        for (int mi = 0; mi < 4; ++mi) {
            bf16x8 bq = *(const bf16x8*)&Qm[(wm * 4 + mi) * 16 + lr][lg * 8];
            f32x4 e = __builtin_amdgcn_mfma_f32_16x16x32_bf16(aq, bq, zero, 0, 0, 0);
            S[0] += fexp2(e[0]); S[1] += fexp2(e[1]);
            S[2] += fexp2(e[2]); S[3] += fexp2(e[3]);
        }
    }
    #pragma unroll
    for (int d = 1; d < 16; d <<= 1) {
        #pragma unroll
        for (int i = 0; i < 4; ++i) S[i] += __shfl_xor(S[i], d);
    }
    if (lr == 0) {
        #pragma unroll
        for (int i = 0; i < 4; ++i) Sred[wm][wn * 16 + lg * 4 + i] = S[i];
    }
    __syncthreads();
    if (tid < 64)
        RSI[b * NN + n0 + tid] = 256.f / (Sred[0][tid] + Sred[1][tid]);
}

// K3: attn + PV + fused final. R14 schedule; V/W through LDS as fp8 e4m3.
// Producers (w 0-7): E(t+1) bf16 + softmax + fp8-W write + fp8-V staging.
// Consumers (w 8-11): PV mfma_f32_32x32x16_fp8_fp8, pacc[2][2] quadrants.
// Epilogue: Us = bf16(x - XR) in LDS (alias V/W pool), wt GEMM bf16, BN+ReLU+res.
__global__ __launch_bounds__(768, 3) void k_attn_pv(const ushort* __restrict__ Qt,
        const uchar* __restrict__ Vb, const float* __restrict__ RSI,
        const float* __restrict__ x, const float* __restrict__ wt,
        const float* __restrict__ bt, const float* __restrict__ gamma,
        const float* __restrict__ beta, const float* __restrict__ bn_mean,
        const float* __restrict__ bn_var, float* __restrict__ out) {
    __shared__ uchar SMp[2][2][128][72];  // [V=0/W=1][buf][row][72B]; epilogue Us alias
    __shared__ ushort wtl[16896];         // wt bf16 [128][132]
    __shared__ float csred[4][128];
    __shared__ float csum[128];
    __shared__ float fAl[128], fBl[128];
    int bid = (blockIdx.x & 7) * 32 + (blockIdx.x >> 3);   // XCD-chunked swizzle
    int b  = bid >> 4;
    int m0 = (bid & 15) << 7;
    int tid = threadIdx.x;
    int w = tid >> 6, l = tid & 63, lr = l & 15, lg = l >> 4;
    const ushort* Qtb = Qt + (size_t)b * NN * CQ;
    const uchar*  Vbb = Vb + (size_t)b * CC * NN;
    const float*  RSb = RSI + (size_t)b * NN;
    const float*  xb  = x   + (size_t)b * CC * NN;
    float*        outb = out + (size_t)b * CC * NN;
    f32x4 zero = {0.f, 0.f, 0.f, 0.f};
    bool producer = (w < 8);

    // ---- stage wt -> wtl (bf16, stride 132) + BN constants ----
    for (int idx = tid; idx < 4096; idx += 768) {
        int r = idx >> 5, c4 = (idx & 31) << 2;
        float4 w4 = *(const float4*)&wt[r * 128 + c4];
        *(ushort4*)&wtl[r * 132 + c4] =
            make_ushort4(f2b(w4.x), f2b(w4.y), f2b(w4.z), f2b(w4.w));
    }
    if (tid < 128) {
        float A = gamma[tid] * rsqrtf(bn_var[tid] + 1e-5f);
        fAl[tid] = A;
        fBl[tid] = (bt[tid] - bn_mean[tid]) * A + beta[tid];
    }

    // ---------------- producer state ----------------
    int wn = w & 3, mh = w >> 2;            // n-strip, m-half
    bf16x8 bm[4];
    float cs[4] = {0.f, 0.f, 0.f, 0.f};
    int sv = 0, shv = 0;
    const uchar* vsrc = nullptr;
    bf16x8 aq_nx; float4 rsi_nx;
    // ---------------- consumer state ----------------
    int cw = w - 8;
    int dh = cw >> 1, mh2 = cw & 1;         // d-half, m-half
    int ar = l & 31, kh = l >> 5;
    f32x16 pacc00, pacc01, pacc10, pacc11;

    if (producer) {
        #pragma unroll
        for (int mi = 0; mi < 4; ++mi)
            bm[mi] = *(const bf16x8*)&Qtb[(size_t)(m0 + (mh * 4 + mi) * 16 + lr) * CQ + lg * 8];
        sv = tid >> 2; shv = (tid & 3) * 16;   // V row, 16-byte chunk
        vsrc = Vbb + (size_t)sv * NN + shv;
        {
            uint4 v0 = *(const uint4*)(vsrc);
            uchar* dst = &SMp[0][0][sv][shv];
            *(uint2*)(dst)     = make_uint2(v0.x, v0.y);
            *(uint2*)(dst + 8) = make_uint2(v0.z, v0.w);
        }
        {
            bf16x8 aq0 = *(const bf16x8*)&Qtb[(size_t)(wn * 16 + lr) * CQ + lg * 8];
            float4 r4 = *(const float4*)&RSb[wn * 16 + lg * 4];
            int nb = wn * 16 + lg * 4;   // byte offset (1B/elem)
            #pragma unroll
            for (int mi = 0; mi < 4; ++mi) {
                f32x4 e = __builtin_amdgcn_mfma_f32_16x16x32_bf16(aq0, bm[mi], zero, 0, 0, 0);
                float w0 = fexp2(e[0]) * r4.x;
                float w1 = fexp2(e[1]) * r4.y;
                float w2 = fexp2(e[2]) * r4.z;
                float w3 = fexp2(e[3]) * r4.w;
                cs[mi] += w0 + w1 + w2 + w3;
                union { uchar b[4]; uint u; } pw;
                pw.b[0] = f2q(w0); pw.b[1] = f2q(w1);
                pw.b[2] = f2q(w2); pw.b[3] = f2q(w3);
                *(uint*)&SMp[1][0][(mh * 4 + mi) * 16 + lr][nb] = pw.u;
            }
        }
        aq_nx  = *(const bf16x8*)&Qtb[(size_t)(64 + wn * 16 + lr) * CQ + lg * 8];
        rsi_nx = *(const float4*)&RSb[64 + wn * 16 + lg * 4];
    } else {
        #pragma unroll
        for (int r = 0; r < 16; ++r) {
            pacc00[r] = 0.f; pacc01[r] = 0.f; pacc10[r] = 0.f; pacc11[r] = 0.f;
        }
    }
    __syncthreads();
    for (int t = 0; t < 32; ++t) {
        int cur = t & 1;
        if (producer) {
            if (t < 31) {
                int ntn = (t + 1) * 64;
                uint4 v0 = *(const uint4*)(vsrc + ntn);
                bf16x8 aq = aq_nx;
                float4 r4 = rsi_nx;
                if (t < 30) {
                    int nt2 = (t + 2) * 64;
                    aq_nx  = *(const bf16x8*)&Qtb[(size_t)(nt2 + wn * 16 + lr) * CQ + lg * 8];
                    rsi_nx = *(const float4*)&RSb[nt2 + wn * 16 + lg * 4];
                }
                int nb = wn * 16 + lg * 4;
                #pragma unroll
                for (int mi = 0; mi < 4; ++mi) {
                    f32x4 e = __builtin_amdgcn_mfma_f32_16x16x32_bf16(aq, bm[mi], zero, 0, 0, 0);
                    float w0 = fexp2(e[0]) * r4.x;
                    float w1 = fexp2(e[1]) * r4.y;
                    float w2 = fexp2(e[2]) * r4.z;
                    float w3 = fexp2(e[3]) * r4.w;
                    cs[mi] += w0 + w1 + w2 + w3;
                    union { uchar b[4]; uint u; } pw;
                    pw.b[0] = f2q(w0); pw.b[1] = f2q(w1);
                    pw.b[2] = f2q(w2); pw.b[3] = f2q(w3);
                    *(uint*)&SMp[1][cur ^ 1][(mh * 4 + mi) * 16 + lr][nb] = pw.u;
                }
                uchar* dst = &SMp[0][cur ^ 1][sv][shv];
                *(uint2*)(dst)     = make_uint2(v0.x, v0.y);
                *(uint2*)(dst + 8) = make_uint2(v0.z, v0.w);
            }
        } else {
            // ---- PV fp8: wave owns d [dh*64,+64) x m [mh2*64,+64) ----
            __builtin_amdgcn_s_setprio(1);
            #pragma unroll
            for (int kk = 0; kk < 4; ++kk) {
                int cb = kk * 16 + kh * 8;    // column byte
                U2L va0, va1, wb0, wb1;
                va0.u = *(const uint2*)&SMp[0][cur][dh * 64 + ar][cb];
                va1.u = *(const uint2*)&SMp[0][cur][dh * 64 + 32 + ar][cb];
                wb0.u = *(const uint2*)&SMp[1][cur][mh2 * 64 + ar][cb];
                wb1.u = *(const uint2*)&SMp[1][cur][mh2 * 64 + 32 + ar][cb];
                pacc00 = __builtin_amdgcn_mfma_f32_32x32x16_fp8_fp8(va0.l, wb0.l, pacc00, 0, 0, 0);
                pacc01 = __builtin_amdgcn_mfma_f32_32x32x16_fp8_fp8(va0.l, wb1.l, pacc01, 0, 0, 0);
                pacc10 = __builtin_amdgcn_mfma_f32_32x32x16_fp8_fp8(va1.l, wb0.l, pacc10, 0, 0, 0);
                pacc11 = __builtin_amdgcn_mfma_f32_32x32x16_fp8_fp8(va1.l, wb1.l, pacc11, 0, 0, 0);
            }
            __builtin_amdgcn_s_setprio(0);
        }
        __syncthreads();
    }
    // ---- colsum reduce ----
    if (producer) {
        #pragma unroll
        for (int mi = 0; mi < 4; ++mi) {
            cs[mi] += __shfl_xor(cs[mi], 16);
            cs[mi] += __shfl_xor(cs[mi], 32);
        }
        if (lg == 0) {
            #pragma unroll
            for (int mi = 0; mi < 4; ++mi)
                csred[wn][(mh * 4 + mi) * 16 + lr] = cs[mi];
        }
    }
    __syncthreads();
    if (tid < 128) {
        float tot = csred[0][tid] + csred[1][tid] + csred[2][tid] + csred[3][tid];
        csum[tid] = 1.f / (2.56e-7f + tot);   // eps*256 (W scaled by 256)
    }
    __syncthreads();
    // ---- consumers: Us[m][c] = bf16(x - XR), alias on SMp, stride 132 ushorts ----
    ushort* UsP = (ushort*)&SMp[0][0][0][0];
    if (!producer) {
        float inv0 = csum[mh2 * 64 + ar];
        float inv1 = csum[mh2 * 64 + 32 + ar];
        int mA = m0 + mh2 * 64 + ar;          // global m
        int mL = mh2 * 64 + ar;               // local m
        #pragma unroll
        for (int g = 0; g < 4; ++g) {
            int db = dh * 64 + 8 * g + 4 * kh;   // 4 consecutive d at db..db+3
            ushort4 u00, u01, u10, u11;
            #pragma unroll
            for (int j = 0; j < 4; ++j) {
                int r = 4 * g + j;
                float x00 = xb[(size_t)(db + j) * NN + mA];
                float x01 = xb[(size_t)(db + j) * NN + mA + 32];
                float x10 = xb[(size_t)(db + 32 + j) * NN + mA];
                float x11 = xb[(size_t)(db + 32 + j) * NN + mA + 32];
                ((ushort*)&u00)[j] = f2b(x00 - pacc00[r] * inv0);
                ((ushort*)&u01)[j] = f2b(x01 - pacc01[r] * inv1);
                ((ushort*)&u10)[j] = f2b(x10 - pacc10[r] * inv0);
                ((ushort*)&u11)[j] = f2b(x11 - pacc11[r] * inv1);
            }
            *(ushort4*)&UsP[mL * 132 + db]             = u00;
            *(ushort4*)&UsP[(mL + 32) * 132 + db]      = u01;
            *(ushort4*)&UsP[mL * 132 + db + 32]        = u10;
            *(ushort4*)&UsP[(mL + 32) * 132 + db + 32] = u11;
        }
    }
    __syncthreads();
    // ---- all waves: t = wt @ Us^T; out = x + relu(t*fA + fB) ----
    for (int tile = w; tile < 16; tile += 12) {
        int rt = tile >> 2, mt = tile & 3;
        f32x16 acc;
        #pragma unroll
        for (int r = 0; r < 16; ++r) acc[r] = 0.f;
        #pragma unroll
        for (int kk = 0; kk < 8; ++kk) {
            const ushort* ap = &wtl[(rt * 32 + ar) * 132 + kk * 16 + kh * 8];
            uint2 a0 = *(const uint2*)ap; uint2 a1 = *(const uint2*)(ap + 4);
            const ushort* bp = &UsP[(mt * 32 + ar) * 132 + kk * 16 + kh * 8];
            uint2 b0 = *(const uint2*)bp; uint2 b1 = *(const uint2*)(bp + 4);
            acc = __builtin_amdgcn_mfma_f32_32x32x16_bf16(
                as_b8_2(a0, a1), as_b8_2(b0, b1), acc, 0, 0, 0);
        }
        int m = m0 + mt * 32 + ar;
        #pragma unroll
        for (int g = 0; g < 4; ++g) {
            #pragma unroll
            for (int j = 0; j < 4; ++j) {
                int r = rt * 32 + j + 8 * g + 4 * kh;
                float t = acc[4 * g + j] * fAl[r] + fBl[r];
                t = fmaxf(t, 0.f);
                outb[(size_t)r * NN + m] = xb[(size_t)r * NN + m] + t;
            }
        }
    }
}

extern "C" void kernel_launch(void* const* d_in, const int* in_sizes, int n_in,
                              void* d_out, int out_size, void* d_ws, size_t ws_size,
                              hipStream_t stream) {
    const float* x       = (const float*)d_in[0];
    const float* wq      = (const float*)d_in[1];
    const float* wv      = (const float*)d_in[2];
    const float* bv      = (const float*)d_in[3];
    const float* wt      = (const float*)d_in[4];
    const float* bt      = (const float*)d_in[5];
    const float* gamma   = (const float*)d_in[6];
    const float* beta    = (const float*)d_in[7];
    const float* bn_mean = (const float*)d_in[8];
    const float* bn_var  = (const float*)d_in[9];
    float* out = (float*)d_out;
    float* ws  = (float*)d_ws;

    ushort* Qt   = (ushort*)ws;
    uchar*  Vbp  = (uchar*)(ws + OFF_VB);
    float*  RSI  = ws + OFF_RSI;

    k_proj<<<BB * 32, 256, 0, stream>>>(x, wq, wv, bv, Qt, Vbp);
    k_rowstats<<<BB * 32, 512, 0, stream>>>(Qt, RSI);
    k_attn_pv<<<BB * 16, 768, 0, stream>>>(Qt, Vbp, RSI, x, wt, bt, gamma, beta,
                                           bn_mean, bn_var, out);
}

// Round 17
// 57.093 us; speedup vs baseline: 1.2041x; 1.1734x over previous
//
#include <hip/hip_runtime.h>
#include <hip/hip_bf16.h>
#include <math.h>

#define BB 16
#define CC 128
#define NN 2048
#define CQ 32   // C/4

typedef __attribute__((ext_vector_type(8))) short bf16x8;
typedef __attribute__((ext_vector_type(4))) float f32x4;
typedef __attribute__((ext_vector_type(16))) float f32x16;
typedef unsigned char uchar;

__device__ __forceinline__ ushort f2b(float f) {
    __hip_bfloat16 h = __float2bfloat16(f);
    return *reinterpret_cast<ushort*>(&h);
}
__device__ __forceinline__ float b2f(ushort u) {
    union { unsigned u; float f; } v; v.u = ((unsigned)u) << 16;
    return v.f;
}
// HW packed f32->fp8(e4m3): 4 floats -> 4 bytes in 2 VALU ops
__device__ __forceinline__ uint f2q4(float a, float b, float c, float d) {
    int r = __builtin_amdgcn_cvt_pk_fp8_f32(a, b, 0, false);
    r = __builtin_amdgcn_cvt_pk_fp8_f32(c, d, r, true);
    return (uint)r;
}
__device__ __forceinline__ bf16x8 as_b8(uint4 u) {
    union { uint4 u; bf16x8 b; } v; v.u = u; return v.b;
}
__device__ __forceinline__ bf16x8 as_b8_2(uint2 a, uint2 b) {
    return as_b8(make_uint4(a.x, a.y, b.x, b.y));
}
__device__ __forceinline__ float fexp2(float x) {
    return __builtin_amdgcn_exp2f(x);   // v_exp_f32: 2^x
}
union U2L { uint2 u; long l; };

// ---------------- workspace layout (float granularity offsets) ----------------
// Qt  : bf16 [B][N][32]   off 0          (wq pre-scaled by sqrt(log2 e))
// Vb  : fp8  [B][128][N]  off 524,288    (e4m3)
// RSI : f32  [B][N]       off 4,718,592  (stores 256/rowsum)
#define OFF_VB  524288
#define OFF_RSI 4718592

#define QSCALE 1.2011224087864498f   // sqrt(log2(e)); E comes out scaled by log2(e)

// K1: MFMA projection. Qt[b,n,d] (d<32, scaled), Vb[b,d,n] = fp8(wv.x + bv).
__global__ __launch_bounds__(256) void k_proj(const float* __restrict__ x,
        const float* __restrict__ wq, const float* __restrict__ wv,
        const float* __restrict__ bv, ushort* __restrict__ Qt, uchar* __restrict__ Vb) {
    __shared__ ushort Wl[160][136];
    __shared__ ushort Xs[64][136];   // [n][c] bf16
    int bid = (blockIdx.x & 7) * 64 + (blockIdx.x >> 3);   // XCD-chunked swizzle
    int b  = bid >> 5;
    int n0 = (bid & 31) << 6;
    int tid = threadIdx.x;
    #pragma unroll
    for (int k = 0; k < 20; ++k) {
        int idx = k * 256 + tid;
        int r = idx >> 5, c4 = (idx & 31) << 2;
        const float* srcw = (r < 32) ? (wq + r * 128 + c4) : (wv + (r - 32) * 128 + c4);
        float4 w4 = *(const float4*)srcw;
        float s = (r < 32) ? QSCALE : 1.0f;
        *(ushort4*)&Wl[r][c4] = make_ushort4(f2b(w4.x * s), f2b(w4.y * s),
                                             f2b(w4.z * s), f2b(w4.w * s));
    }
    const float* xb = x + (size_t)b * CC * NN;
    for (int idx = tid; idx < 2048; idx += 256) {
        int c = idx >> 4, n4 = (idx & 15) << 2;
        float4 xv = *(const float4*)&xb[c * NN + n0 + n4];
        Xs[n4][c]     = f2b(xv.x);
        Xs[n4 + 1][c] = f2b(xv.y);
        Xs[n4 + 2][c] = f2b(xv.z);
        Xs[n4 + 3][c] = f2b(xv.w);
    }
    __syncthreads();
    int w = tid >> 6, l = tid & 63, lr = l & 15, lg = l >> 4;
    f32x4 zero = {0.f, 0.f, 0.f, 0.f};
    int nn = n0 + w * 16 + lr;
    for (int dt = 0; dt < 10; ++dt) {
        f32x4 acc = zero;
        #pragma unroll
        for (int k = 0; k < 4; ++k) {
            bf16x8 a  = *(const bf16x8*)&Wl[dt * 16 + lr][k * 32 + lg * 8];
            bf16x8 bx = *(const bf16x8*)&Xs[w * 16 + lr][k * 32 + lg * 8];
            acc = __builtin_amdgcn_mfma_f32_16x16x32_bf16(a, bx, acc, 0, 0, 0);
        }
        if (dt < 2) {
            ushort4 p = make_ushort4(f2b(acc[0]), f2b(acc[1]), f2b(acc[2]), f2b(acc[3]));
            *(ushort4*)&Qt[(size_t)(b * NN + nn) * CQ + dt * 16 + lg * 4] = p;
        } else {
            union { uint u; uchar c[4]; } q;
            int vd = (dt - 2) * 16 + lg * 4;
            q.u = f2q4(acc[0] + bv[vd], acc[1] + bv[vd + 1],
                       acc[2] + bv[vd + 2], acc[3] + bv[vd + 3]);
            #pragma unroll
            for (int i = 0; i < 4; ++i)
                Vb[(size_t)(b * CC + vd + i) * NN + nn] = q.c[i];
        }
    }
}

// K2: row softmax denominators. RSI = 256/rowsum (fp8-W scaling folded in).
__global__ __launch_bounds__(512) void k_rowstats(const ushort* __restrict__ Qt,
        float* __restrict__ RSI) {
    __shared__ ushort Qm[128][36];
    __shared__ float Sred[2][64];
    int bid = (blockIdx.x & 7) * 64 + (blockIdx.x >> 3);
    int b  = bid >> 5;
    int n0 = (bid & 31) << 6;
    int tid = threadIdx.x;
    int w = tid >> 6, l = tid & 63, lr = l & 15, lg = l >> 4;
    int wn = w & 3, wm = w >> 2;
    const ushort* Qtb = Qt + (size_t)b * NN * CQ;
    bf16x8 aq = *(const bf16x8*)&Qtb[(size_t)(n0 + wn * 16 + lr) * CQ + lg * 8];
    int sr = tid >> 2, sc = (tid & 3) * 8;
    uint4 q0 = *(const uint4*)&Qtb[(size_t)sr * CQ + sc];
    float S[4] = {0.f, 0.f, 0.f, 0.f};
    f32x4 zero = {0.f, 0.f, 0.f, 0.f};
    for (int t = 0; t < 16; ++t) {
        __syncthreads();
        *(uint4*)&Qm[sr][sc] = q0;
        __syncthreads();
        if (t < 15)
            q0 = *(const uint4*)&Qtb[(size_t)((t + 1) * 128 + sr) * CQ + sc];
        #pragma unroll
        for (int mi = 0; mi < 4; ++mi) {
            bf16x8 bq = *(const bf16x8*)&Qm[(wm * 4 + mi) * 16 + lr][lg * 8];
            f32x4 e = __builtin_amdgcn_mfma_f32_16x16x32_bf16(aq, bq, zero, 0, 0, 0);
            S[0] += fexp2(e[0]); S[1] += fexp2(e[1]);
            S[2] += fexp2(e[2]); S[3] += fexp2(e[3]);
        }
    }
    #pragma unroll
    for (int d = 1; d < 16; d <<= 1) {
        #pragma unroll
        for (int i = 0; i < 4; ++i) S[i] += __shfl_xor(S[i], d);
    }
    if (lr == 0) {
        #pragma unroll
        for (int i = 0; i < 4; ++i) Sred[wm][wn * 16 + lg * 4 + i] = S[i];
    }
    __syncthreads();
    if (tid < 64)
        RSI[b * NN + n0 + tid] = 256.f / (Sred[0][tid] + Sred[1][tid]);
}

// K3: attn + PV + fused final. R14 schedule; V/W through LDS as fp8 e4m3
// with HW cvt_pk_fp8 packing.
__global__ __launch_bounds__(768, 3) void k_attn_pv(const ushort* __restrict__ Qt,
        const uchar* __restrict__ Vb, const float* __restrict__ RSI,
        const float* __restrict__ x, const float* __restrict__ wt,
        const float* __restrict__ bt, const float* __restrict__ gamma,
        const float* __restrict__ beta, const float* __restrict__ bn_mean,
        const float* __restrict__ bn_var, float* __restrict__ out) {
    __shared__ uchar SMp[2][2][128][72];  // [V=0/W=1][buf][row][72B]; epilogue Us alias
    __shared__ ushort wtl[16896];         // wt bf16 [128][132]
    __shared__ float csred[4][128];
    __shared__ float csum[128];
    __shared__ float fAl[128], fBl[128];
    int bid = (blockIdx.x & 7) * 32 + (blockIdx.x >> 3);   // XCD-chunked swizzle
    int b  = bid >> 4;
    int m0 = (bid & 15) << 7;
    int tid = threadIdx.x;
    int w = tid >> 6, l = tid & 63, lr = l & 15, lg = l >> 4;
    const ushort* Qtb = Qt + (size_t)b * NN * CQ;
    const uchar*  Vbb = Vb + (size_t)b * CC * NN;
    const float*  RSb = RSI + (size_t)b * NN;
    const float*  xb  = x   + (size_t)b * CC * NN;
    float*        outb = out + (size_t)b * CC * NN;
    f32x4 zero = {0.f, 0.f, 0.f, 0.f};
    bool producer = (w < 8);

    // ---- stage wt -> wtl (bf16, stride 132) + BN constants ----
    for (int idx = tid; idx < 4096; idx += 768) {
        int r = idx >> 5, c4 = (idx & 31) << 2;
        float4 w4 = *(const float4*)&wt[r * 128 + c4];
        *(ushort4*)&wtl[r * 132 + c4] =
            make_ushort4(f2b(w4.x), f2b(w4.y), f2b(w4.z), f2b(w4.w));
    }
    if (tid < 128) {
        float A = gamma[tid] * rsqrtf(bn_var[tid] + 1e-5f);
        fAl[tid] = A;
        fBl[tid] = (bt[tid] - bn_mean[tid]) * A + beta[tid];
    }

    // ---------------- producer state ----------------
    int wn = w & 3, mh = w >> 2;            // n-strip, m-half
    bf16x8 bm[4];
    float cs[4] = {0.f, 0.f, 0.f, 0.f};
    int sv = 0, shv = 0;
    const uchar* vsrc = nullptr;
    bf16x8 aq_nx; float4 rsi_nx;
    // ---------------- consumer state ----------------
    int cw = w - 8;
    int dh = cw >> 1, mh2 = cw & 1;         // d-half, m-half
    int ar = l & 31, kh = l >> 5;
    f32x16 pacc00, pacc01, pacc10, pacc11;

    if (producer) {
        #pragma unroll
        for (int mi = 0; mi < 4; ++mi)
            bm[mi] = *(const bf16x8*)&Qtb[(size_t)(m0 + (mh * 4 + mi) * 16 + lr) * CQ + lg * 8];
        sv = tid >> 2; shv = (tid & 3) * 16;   // V row, 16-byte chunk
        vsrc = Vbb + (size_t)sv * NN + shv;
        {
            uint4 v0 = *(const uint4*)(vsrc);
            uchar* dst = &SMp[0][0][sv][shv];
            *(uint2*)(dst)     = make_uint2(v0.x, v0.y);
            *(uint2*)(dst + 8) = make_uint2(v0.z, v0.w);
        }
        {
            bf16x8 aq0 = *(const bf16x8*)&Qtb[(size_t)(wn * 16 + lr) * CQ + lg * 8];
            float4 r4 = *(const float4*)&RSb[wn * 16 + lg * 4];
            int nb = wn * 16 + lg * 4;   // byte offset (1B/elem)
            #pragma unroll
            for (int mi = 0; mi < 4; ++mi) {
                f32x4 e = __builtin_amdgcn_mfma_f32_16x16x32_bf16(aq0, bm[mi], zero, 0, 0, 0);
                float w0 = fexp2(e[0]) * r4.x;
                float w1 = fexp2(e[1]) * r4.y;
                float w2 = fexp2(e[2]) * r4.z;
                float w3 = fexp2(e[3]) * r4.w;
                cs[mi] += w0 + w1 + w2 + w3;
                *(uint*)&SMp[1][0][(mh * 4 + mi) * 16 + lr][nb] = f2q4(w0, w1, w2, w3);
            }
        }
        aq_nx  = *(const bf16x8*)&Qtb[(size_t)(64 + wn * 16 + lr) * CQ + lg * 8];
        rsi_nx = *(const float4*)&RSb[64 + wn * 16 + lg * 4];
    } else {
        #pragma unroll
        for (int r = 0; r < 16; ++r) {
            pacc00[r] = 0.f; pacc01[r] = 0.f; pacc10[r] = 0.f; pacc11[r] = 0.f;
        }
    }
    __syncthreads();
    for (int t = 0; t < 32; ++t) {
        int cur = t & 1;
        if (producer) {
            if (t < 31) {
                int ntn = (t + 1) * 64;
                uint4 v0 = *(const uint4*)(vsrc + ntn);
                bf16x8 aq = aq_nx;
                float4 r4 = rsi_nx;
                if (t < 30) {
                    int nt2 = (t + 2) * 64;
                    aq_nx  = *(const bf16x8*)&Qtb[(size_t)(nt2 + wn * 16 + lr) * CQ + lg * 8];
                    rsi_nx = *(const float4*)&RSb[nt2 + wn * 16 + lg * 4];
                }
                int nb = wn * 16 + lg * 4;
                #pragma unroll
                for (int mi = 0; mi < 4; ++mi) {
                    f32x4 e = __builtin_amdgcn_mfma_f32_16x16x32_bf16(aq, bm[mi], zero, 0, 0, 0);
                    float w0 = fexp2(e[0]) * r4.x;
                    float w1 = fexp2(e[1]) * r4.y;
                    float w2 = fexp2(e[2]) * r4.z;
                    float w3 = fexp2(e[3]) * r4.w;
                    cs[mi] += w0 + w1 + w2 + w3;
                    *(uint*)&SMp[1][cur ^ 1][(mh * 4 + mi) * 16 + lr][nb] =
                        f2q4(w0, w1, w2, w3);
                }
                uchar* dst = &SMp[0][cur ^ 1][sv][shv];
                *(uint2*)(dst)     = make_uint2(v0.x, v0.y);
                *(uint2*)(dst + 8) = make_uint2(v0.z, v0.w);
            }
        } else {
            // ---- PV fp8: wave owns d [dh*64,+64) x m [mh2*64,+64) ----
            __builtin_amdgcn_s_setprio(1);
            #pragma unroll
            for (int kk = 0; kk < 4; ++kk) {
                int cb = kk * 16 + kh * 8;    // column byte
                U2L va0, va1, wb0, wb1;
                va0.u = *(const uint2*)&SMp[0][cur][dh * 64 + ar][cb];
                va1.u = *(const uint2*)&SMp[0][cur][dh * 64 + 32 + ar][cb];
                wb0.u = *(const uint2*)&SMp[1][cur][mh2 * 64 + ar][cb];
                wb1.u = *(const uint2*)&SMp[1][cur][mh2 * 64 + 32 + ar][cb];
                pacc00 = __builtin_amdgcn_mfma_f32_32x32x16_fp8_fp8(va0.l, wb0.l, pacc00, 0, 0, 0);
                pacc01 = __builtin_amdgcn_mfma_f32_32x32x16_fp8_fp8(va0.l, wb1.l, pacc01, 0, 0, 0);
                pacc10 = __builtin_amdgcn_mfma_f32_32x32x16_fp8_fp8(va1.l, wb0.l, pacc10, 0, 0, 0);
                pacc11 = __builtin_amdgcn_mfma_f32_32x32x16_fp8_fp8(va1.l, wb1.l, pacc11, 0, 0, 0);
            }
            __builtin_amdgcn_s_setprio(0);
        }
        __syncthreads();
    }
    // ---- colsum reduce ----
    if (producer) {
        #pragma unroll
        for (int mi = 0; mi < 4; ++mi) {
            cs[mi] += __shfl_xor(cs[mi], 16);
            cs[mi] += __shfl_xor(cs[mi], 32);
        }
        if (lg == 0) {
            #pragma unroll
            for (int mi = 0; mi < 4; ++mi)
                csred[wn][(mh * 4 + mi) * 16 + lr] = cs[mi];
        }
    }
    __syncthreads();
    if (tid < 128) {
        float tot = csred[0][tid] + csred[1][tid] + csred[2][tid] + csred[3][tid];
        csum[tid] = 1.f / (2.56e-7f + tot);   // eps*256 (W scaled by 256)
    }
    __syncthreads();
    // ---- consumers: Us[m][c] = bf16(x - XR), alias on SMp, stride 132 ushorts ----
    ushort* UsP = (ushort*)&SMp[0][0][0][0];
    if (!producer) {
        float inv0 = csum[mh2 * 64 + ar];
        float inv1 = csum[mh2 * 64 + 32 + ar];
        int mA = m0 + mh2 * 64 + ar;          // global m
        int mL = mh2 * 64 + ar;               // local m
        #pragma unroll
        for (int g = 0; g < 4; ++g) {
            int db = dh * 64 + 8 * g + 4 * kh;   // 4 consecutive d at db..db+3
            ushort4 u00, u01, u10, u11;
            #pragma unroll
            for (int j = 0; j < 4; ++j) {
                int r = 4 * g + j;
                float x00 = xb[(size_t)(db + j) * NN + mA];
                float x01 = xb[(size_t)(db + j) * NN + mA + 32];
                float x10 = xb[(size_t)(db + 32 + j) * NN + mA];
                float x11 = xb[(size_t)(db + 32 + j) * NN + mA + 32];
                ((ushort*)&u00)[j] = f2b(x00 - pacc00[r] * inv0);
                ((ushort*)&u01)[j] = f2b(x01 - pacc01[r] * inv1);
                ((ushort*)&u10)[j] = f2b(x10 - pacc10[r] * inv0);
                ((ushort*)&u11)[j] = f2b(x11 - pacc11[r] * inv1);
            }
            *(ushort4*)&UsP[mL * 132 + db]             = u00;
            *(ushort4*)&UsP[(mL + 32) * 132 + db]      = u01;
            *(ushort4*)&UsP[mL * 132 + db + 32]        = u10;
            *(ushort4*)&UsP[(mL + 32) * 132 + db + 32] = u11;
        }
    }
    __syncthreads();
    // ---- all waves: t = wt @ Us^T; out = x + relu(t*fA + fB) ----
    for (int tile = w; tile < 16; tile += 12) {
        int rt = tile >> 2, mt = tile & 3;
        f32x16 acc;
        #pragma unroll
        for (int r = 0; r < 16; ++r) acc[r] = 0.f;
        #pragma unroll
        for (int kk = 0; kk < 8; ++kk) {
            const ushort* ap = &wtl[(rt * 32 + ar) * 132 + kk * 16 + kh * 8];
            uint2 a0 = *(const uint2*)ap; uint2 a1 = *(const uint2*)(ap + 4);
            const ushort* bp = &UsP[(mt * 32 + ar) * 132 + kk * 16 + kh * 8];
            uint2 b0 = *(const uint2*)bp; uint2 b1 = *(const uint2*)(bp + 4);
            acc = __builtin_amdgcn_mfma_f32_32x32x16_bf16(
                as_b8_2(a0, a1), as_b8_2(b0, b1), acc, 0, 0, 0);
        }
        int m = m0 + mt * 32 + ar;
        #pragma unroll
        for (int g = 0; g < 4; ++g) {
            #pragma unroll
            for (int j = 0; j < 4; ++j) {
                int r = rt * 32 + j + 8 * g + 4 * kh;
                float t = acc[4 * g + j] * fAl[r] + fBl[r];
                t = fmaxf(t, 0.f);
                outb[(size_t)r * NN + m] = xb[(size_t)r * NN + m] + t;
            }
        }
    }
}

extern "C" void kernel_launch(void* const* d_in, const int* in_sizes, int n_in,
                              void* d_out, int out_size, void* d_ws, size_t ws_size,
                              hipStream_t stream) {
    const float* x       = (const float*)d_in[0];
    const float* wq      = (const float*)d_in[1];
    const float* wv      = (const float*)d_in[2];
    const float* bv      = (const float*)d_in[3];
    const float* wt      = (const float*)d_in[4];
    const float* bt      = (const float*)d_in[5];
    const float* gamma   = (const float*)d_in[6];
    const float* beta    = (const float*)d_in[7];
    const float* bn_mean = (const float*)d_in[8];
    const float* bn_var  = (const float*)d_in[9];
    float* out = (float*)d_out;
    float* ws  = (float*)d_ws;

    ushort* Qt   = (ushort*)ws;
    uchar*  Vbp  = (uchar*)(ws + OFF_VB);
    float*  RSI  = ws + OFF_RSI;

    k_proj<<<BB * 32, 256, 0, stream>>>(x, wq, wv, bv, Qt, Vbp);
    k_rowstats<<<BB * 32, 512, 0, stream>>>(Qt, RSI);
    k_attn_pv<<<BB * 16, 768, 0, stream>>>(Qt, Vbp, RSI, x, wt, bt, gamma, beta,
                                           bn_mean, bn_var, out);
}